// Round 5
// baseline (176.752 us; speedup 1.0000x reference)
//
#include <hip/hip_runtime.h>
#include <math.h>

// DLP loss: ce(scores,target) + 25 * sum_i sum_{k<m_i} ||f_i - f_{nbr_k}/m_i||^2
// m_i = min(#same-label (excl self), 20), neighbors by eps-shifted L1 distance.
//
//  K1 dist_kernel     : 528 upper-triangle 64x64 supertiles. 256 thr = 2 wave-
//                       pairs; K split across pairs (128 c each), each pair does
//                       the full 64x64 tile at 8x4 cells/thread -> 12 b128 LDS
//                       reads per 256 VALU inst (LDS pipe no longer the limit).
//                       Pair partials combined via LDS; mirror-store off-diag.
//  K2 select_kernel   : 1 wave/row, row register-resident, <=20 butterfly argmin
//                       extractions, contribution written to D[i,i] (no atomics).
//  K3 finalize_kernel : 1 block. out[0] = cross-entropy + sum_i D[i,i].

constexpr float EPS      = 1e-6f;
constexpr int   KSEL     = 20;
constexpr float LAM_HALF = 25.0f;   // 50 * 0.5

#define LDP 68   // row stride (words): 68 mod 32 = 4 -> A broadcast, B 2-way (free)

__device__ __forceinline__ float finf() { return __builtin_inff(); }

// ---------------- K1: masked pairwise eps-shifted L1, upper triangle ----------------
// D[i][j] = sum_c |(F[i][c]+EPS) - F[j][c]| if same label && i!=j else +inf
__global__ __launch_bounds__(256) void dist_kernel(const float* __restrict__ F,
                                                   const int* __restrict__ T,
                                                   float* __restrict__ D,
                                                   int N, int C, int NB) {
    // blockIdx.x -> supertile (bi,bj), bi <= bj < NB
    const int st = blockIdx.x;
    int bi = 0;
    while ((bi + 1) * NB - ((bi + 1) * bi) / 2 <= st) ++bi;
    const int bj = bi + (st - (bi * NB - (bi * (bi - 1)) / 2));
    const int i0 = bi * 64;
    const int j0 = bj * 64;
    const bool mirror = (bi != bj);

    // [h][row][c] with h = K-half; per-half row stride LDP
    __shared__ float As[2 * 64 * LDP];
    __shared__ float Bs[2 * 64 * LDP];

    const int tid    = threadIdx.x;
    const int p      = tid >> 7;       // wave-pair: 0 (waves 0-1), 1 (waves 2-3)
    const int t128   = tid & 127;
    const int tx     = t128 & 15;      // j = tx + 16*s, s<4
    const int ty     = t128 >> 4;      // i = ty*8 + r, r<8

    float acc[8][4];
#pragma unroll
    for (int r = 0; r < 8; ++r)
#pragma unroll
        for (int s = 0; s < 4; ++s) acc[r][s] = 0.f;

    for (int k = 0; k < 2; ++k) {
        // stage both K-halves of 64-c columns: col = k*64 + h*128 + c4
#pragma unroll
        for (int it = 0; it < 8; ++it) {
            int slot = tid + it * 256;          // 0..2047
            int row  = slot >> 5;               // 64 rows
            int wr   = slot & 31;               // 32 float4 per row
            int h    = wr >> 4;
            int c4   = (wr & 15) << 2;
            int col  = k * 64 + h * 128 + c4;
            float4 av = *(const float4*)&F[(size_t)(i0 + row) * C + col];
            av.x += EPS; av.y += EPS; av.z += EPS; av.w += EPS;
            *(float4*)&As[(h * 64 + row) * LDP + c4] = av;
            float4 bv = *(const float4*)&F[(size_t)(j0 + row) * C + col];
            *(float4*)&Bs[(h * 64 + row) * LDP + c4] = bv;
        }
        __syncthreads();

        const int hb = p * 64 * LDP;            // this pair's K-half base
#pragma unroll 2
        for (int c4 = 0; c4 < 64; c4 += 4) {
            float4 a[8], b[4];
#pragma unroll
            for (int r = 0; r < 8; ++r) a[r] = *(const float4*)&As[hb + (ty * 8 + r) * LDP + c4];
#pragma unroll
            for (int s = 0; s < 4; ++s) b[s] = *(const float4*)&Bs[hb + (tx + 16 * s) * LDP + c4];
#pragma unroll
            for (int r = 0; r < 8; ++r)
#pragma unroll
                for (int s = 0; s < 4; ++s) {
                    acc[r][s] += (fabsf(a[r].x - b[s].x) + fabsf(a[r].y - b[s].y))
                               + (fabsf(a[r].z - b[s].z) + fabsf(a[r].w - b[s].w));
                }
        }
        __syncthreads();
    }

    // combine pair-1 partials into pair-0 via LDS (stride 36 words: banks spread)
    if (p == 1) {
#pragma unroll
        for (int r = 0; r < 8; ++r) {
            float4 o = make_float4(acc[r][0], acc[r][1], acc[r][2], acc[r][3]);
            *(float4*)&As[t128 * 36 + r * 4] = o;
        }
    }
    __syncthreads();
    if (p == 0) {
#pragma unroll
        for (int r = 0; r < 8; ++r) {
            float4 o = *(const float4*)&As[t128 * 36 + r * 4];
            acc[r][0] += o.x; acc[r][1] += o.y; acc[r][2] += o.z; acc[r][3] += o.w;
        }

        int ti[8], tj[4];
#pragma unroll
        for (int r = 0; r < 8; ++r) ti[r] = T[i0 + ty * 8 + r];
#pragma unroll
        for (int s = 0; s < 4; ++s) tj[s] = T[j0 + tx + 16 * s];
#pragma unroll
        for (int r = 0; r < 8; ++r) {
            const int i = i0 + ty * 8 + r;
#pragma unroll
            for (int s = 0; s < 4; ++s) {
                const int j = j0 + tx + 16 * s;
                float val = (tj[s] == ti[r] && j != i) ? acc[r][s] : finf();
                D[(size_t)i * N + j] = val;
                if (mirror) D[(size_t)j * N + i] = val;   // eps asymmetry << tolerance
            }
        }
    }
}

// ---------------- K2: per-row top-20 + contribution -> D[i,i] ----------------
// one wave per row; slot (q,e) of lane l holds j = 4*(q*64 + l) + e
__global__ __launch_bounds__(64) void select_kernel(const float* __restrict__ F,
                                                    float* __restrict__ D,
                                                    int N, int C) {
    __shared__ int ssel[KSEL];
    const int i    = blockIdx.x;
    const int lane = threadIdx.x;
    const float4* drow = (const float4*)(D + (size_t)i * N);

    float v[32];
#pragma unroll
    for (int q = 0; q < 8; ++q) {
        float4 t = drow[q * 64 + lane];
        v[q * 4 + 0] = t.x; v[q * 4 + 1] = t.y;
        v[q * 4 + 2] = t.z; v[q * 4 + 3] = t.w;
    }

    float lmin = finf();
#pragma unroll
    for (int s = 0; s < 32; ++s) lmin = fminf(lmin, v[s]);

    int m = 0;
    for (int k = 0; k < KSEL; ++k) {
        float w = lmin;
#pragma unroll
        for (int o = 1; o < 64; o <<= 1) w = fminf(w, __shfl_xor(w, o, 64));
        if (!(w < 1e37f)) break;
        unsigned long long mask = __ballot(lmin == w);
        int winner = (int)__builtin_ctzll(mask);
        if (lane == winner) {
            bool found = false;
            int  jw = 0;
#pragma unroll
            for (int s = 0; s < 32; ++s) {
                bool hit = !found && (v[s] == w);
                if (hit) { jw = 4 * ((s >> 2) * 64 + lane) + (s & 3); v[s] = finf(); found = true; }
            }
            ssel[k] = jw;
            float nm = finf();
#pragma unroll
            for (int s = 0; s < 32; ++s) nm = fminf(nm, v[s]);
            lmin = nm;
        }
        ++m;
    }
    __syncthreads();

    float total = 0.f;
    if (m > 0) {
        const float inv = 1.f / (float)m;
        float4 fi = ((const float4*)(F + (size_t)i * C))[lane];
        float acc = 0.f;
        for (int k = 0; k < m; ++k) {
            const int j = ssel[k];
            float4 fj = ((const float4*)(F + (size_t)j * C))[lane];
            float dx = fi.x - fj.x * inv;
            float dy = fi.y - fj.y * inv;
            float dz = fi.z - fj.z * inv;
            float dw = fi.w - fj.w * inv;
            acc += (dx * dx + dy * dy) + (dz * dz + dw * dw);
        }
        for (int o = 32; o > 0; o >>= 1) acc += __shfl_down(acc, o, 64);
        total = LAM_HALF * acc;
    }
    if (lane == 0) D[(size_t)i * N + i] = total;   // per-row partial, no atomics
}

// ---------------- K3: out[0] = cross-entropy(mean) + sum_i D[i,i] ----------------
__global__ __launch_bounds__(256) void finalize_kernel(const float* __restrict__ scores,
                                                       const int* __restrict__ target,
                                                       const float* __restrict__ D,
                                                       float* __restrict__ out,
                                                       int N, int NC) {
    int tid = threadIdx.x;
    float ce = 0.f, dg = 0.f;
    for (int r = tid; r < N; r += 256) {
        const float* s = scores + (size_t)r * NC;
        float mx = -3.4e38f;
        for (int c = 0; c < NC; ++c) mx = fmaxf(mx, s[c]);
        float sum = 0.f;
        for (int c = 0; c < NC; ++c) sum += __expf(s[c] - mx);
        ce += mx + __logf(sum) - s[target[r]];
        dg += D[(size_t)r * N + r];
    }
    __shared__ float redc[4], redd[4];
    for (int o = 32; o > 0; o >>= 1) { ce += __shfl_down(ce, o, 64); dg += __shfl_down(dg, o, 64); }
    int wid = tid >> 6, lane = tid & 63;
    if (lane == 0) { redc[wid] = ce; redd[wid] = dg; }
    __syncthreads();
    if (tid == 0)
        out[0] = (redc[0] + redc[1] + redc[2] + redc[3]) / (float)N
               + (redd[0] + redd[1] + redd[2] + redd[3]);
}

extern "C" void kernel_launch(void* const* d_in, const int* in_sizes, int n_in,
                              void* d_out, int out_size, void* d_ws, size_t ws_size,
                              hipStream_t stream) {
    const float* feature = (const float*)d_in[0];
    const float* scores  = (const float*)d_in[1];
    const int*   target  = (const int*)d_in[2];
    const int N  = in_sizes[2];
    const int C  = in_sizes[0] / N;
    const int NC = in_sizes[1] / N;
    float* out = (float*)d_out;
    float* D   = (float*)d_ws;                   // N*N*4 bytes (16 MB @ N=2048)
    const int NB = N / 64;

    const int nblk = NB * (NB + 1) / 2;          // 528 upper-triangle supertiles
    dist_kernel<<<nblk, 256, 0, stream>>>(feature, target, D, N, C, NB);

    select_kernel<<<N, 64, 0, stream>>>(feature, D, N, C);

    finalize_kernel<<<1, 256, 0, stream>>>(scores, target, D, out, N, NC);
}

// Round 6
// 130.178 us; speedup vs baseline: 1.3578x; 1.3578x over previous
//
#include <hip/hip_runtime.h>
#include <math.h>

// DLP loss: ce(scores,target) + 25 * sum_i sum_{k<m_i} ||f_i - f_{nbr_k}/m_i||^2
// m_i = min(#same-label (excl self), 20), neighbors by eps-shifted L1 distance.
//
// KEY RESTRUCTURE (R6): neighbors only come from the SAME class. Class-sort the
// rows (stable counting sort -> preserves reference tie order), then compute
// per-class pairwise distances only: sum n_c^2 ~ N^2/8 work, and the compact
// class-local D (N x 512 = 4 MB) is L2-resident for select.
//
//  K0 setup_kernel    : 1 block. stable class-sort -> perm, cls_start, and the
//                       per-class upper-triangle 64x64 tile table.
//  K1 dist_kernel     : one block per class-tile (<=528, ~100 active), 4x4 reg
//                       blocking, b128 LDS reads, eps folded into A staging,
//                       mirror-store off-diagonal tiles (eps asym << tolerance).
//  K2 select_kernel   : 1 wave/row-slot, 8 regs/lane row, <=20 butterfly argmin
//                       extractions, contribution -> P[slot] (no atomics).
//  K3 finalize_kernel : 1 block. out[0] = cross-entropy + sum(P).

constexpr float EPS      = 1e-6f;
constexpr int   KSEL     = 20;
constexpr float LAM_HALF = 25.0f;   // 50 * 0.5
constexpr int   NCLS     = 8;

#define MAXC 512   // padded class-local row length (max class size << 512)
#define LDP  68    // LDS row stride (words): A broadcast, B 2-way (free)

__device__ __forceinline__ float finf() { return __builtin_inff(); }

// meta layout (ints), placed after Dc in ws:
//   [0, N)      perm: slot -> original row (class-grouped, index-ascending)
//   [N, N+9)    cls_start (exclusive prefix, cls_start[8] = N)
//   [N+16]      n_tiles
//   [N+32, ...) tile_tab: (class<<16)|(bi<<8)|bj, bi<=bj  (<=528 entries)

// ---------------- K0: stable class-sort + tile table ----------------
__global__ __launch_bounds__(256) void setup_kernel(const int* __restrict__ T,
                                                    int N, int* __restrict__ meta) {
    __shared__ int cnt[256 * NCLS];   // 8 KB
    __shared__ int cstart[NCLS + 1];
    const int tid = threadIdx.x;
    const int per = N / 256;          // 8 @ N=2048

    int lc[NCLS];
    int myT[16];
#pragma unroll
    for (int c = 0; c < NCLS; ++c) lc[c] = 0;
    for (int q = 0; q < per; ++q) {
        int t = T[tid * per + q];
        myT[q] = t;
        ++lc[t];
    }
#pragma unroll
    for (int c = 0; c < NCLS; ++c) cnt[tid * NCLS + c] = lc[c];
    __syncthreads();

    // per-class exclusive scan over threads (8 threads, serial over 256)
    if (tid < NCLS) {
        int off = 0;
        for (int t = 0; t < 256; ++t) {
            int v = cnt[t * NCLS + tid];
            cnt[t * NCLS + tid] = off;
            off += v;
        }
        cstart[tid] = off;            // class totals, temporarily
    }
    __syncthreads();
    if (tid == 0) {
        int tot[NCLS], acc = 0;
        for (int c = 0; c < NCLS; ++c) tot[c] = cstart[c];
        for (int c = 0; c < NCLS; ++c) { cstart[c] = acc; acc += tot[c]; }
        cstart[NCLS] = acc;           // == N
        for (int c = 0; c <= NCLS; ++c) meta[N + c] = cstart[c];
        // per-class upper-triangle 64-tile table
        int nt = 0;
        for (int c = 0; c < NCLS; ++c) {
            int nb = (tot[c] + 63) >> 6;
            for (int bi = 0; bi < nb; ++bi)
                for (int bj = bi; bj < nb; ++bj)
                    meta[N + 32 + nt++] = (c << 16) | (bi << 8) | bj;
        }
        meta[N + 16] = nt;
    }
    __syncthreads();

    // stable scatter: thread t owns contiguous rows [t*per, (t+1)*per)
    int rc[NCLS];
#pragma unroll
    for (int c = 0; c < NCLS; ++c) rc[c] = 0;
    for (int q = 0; q < per; ++q) {
        int t = myT[q];
        int pos = cstart[t] + cnt[tid * NCLS + t] + rc[t]++;
        meta[pos] = tid * per + q;
    }
}

// ---------------- K1: per-class masked pairwise eps-shifted L1 ----------------
// Dc[slot][jl] = sum_c |(F[i][c]+EPS) - F[j][c]| for same-class pairs, inf on diag
__global__ __launch_bounds__(256) void dist_kernel(const float* __restrict__ F,
                                                   const int* __restrict__ meta,
                                                   float* __restrict__ Dc,
                                                   int N, int C) {
    const int nt = meta[N + 16];
    if ((int)blockIdx.x >= nt) return;
    const int e    = meta[N + 32 + blockIdx.x];
    const int c    = e >> 16, bi = (e >> 8) & 255, bj = e & 255;
    const int base = meta[N + c];
    const int ncls = meta[N + c + 1] - base;
    const int i0 = bi * 64, j0 = bj * 64;
    const bool mirror = (bi != bj);

    __shared__ float As[64 * LDP];
    __shared__ float Bs[64 * LDP];
    __shared__ int gi[64], gj[64];

    const int tid = threadIdx.x;
    const int tx = tid & 15, ty = tid >> 4;

    if (tid < 64)       gi[tid]      = meta[base + min(i0 + tid, ncls - 1)];
    else if (tid < 128) gj[tid - 64] = meta[base + min(j0 + (tid - 64), ncls - 1)];
    __syncthreads();

    float acc[4][4];
#pragma unroll
    for (int r = 0; r < 4; ++r)
#pragma unroll
        for (int s = 0; s < 4; ++s) acc[r][s] = 0.f;

    for (int ck = 0; ck < C; ck += 64) {
#pragma unroll
        for (int it = 0; it < 4; ++it) {
            int slot = tid + it * 256;
            int row  = slot >> 4;
            int c4   = (slot & 15) << 2;
            float4 av = *(const float4*)&F[(size_t)gi[row] * C + ck + c4];
            av.x += EPS; av.y += EPS; av.z += EPS; av.w += EPS;
            *(float4*)&As[row * LDP + c4] = av;
            *(float4*)&Bs[row * LDP + c4] =
                *(const float4*)&F[(size_t)gj[row] * C + ck + c4];
        }
        __syncthreads();
#pragma unroll 4
        for (int c4 = 0; c4 < 64; c4 += 4) {
            float4 a[4], b[4];
#pragma unroll
            for (int r = 0; r < 4; ++r) a[r] = *(const float4*)&As[(ty * 4 + r) * LDP + c4];
#pragma unroll
            for (int s = 0; s < 4; ++s) b[s] = *(const float4*)&Bs[(tx + 16 * s) * LDP + c4];
#pragma unroll
            for (int r = 0; r < 4; ++r)
#pragma unroll
                for (int s = 0; s < 4; ++s) {
                    acc[r][s] += (fabsf(a[r].x - b[s].x) + fabsf(a[r].y - b[s].y))
                               + (fabsf(a[r].z - b[s].z) + fabsf(a[r].w - b[s].w));
                }
        }
        __syncthreads();
    }

#pragma unroll
    for (int r = 0; r < 4; ++r) {
        const int il = i0 + ty * 4 + r;
        if (il >= ncls) continue;
#pragma unroll
        for (int s = 0; s < 4; ++s) {
            const int jl = j0 + tx + 16 * s;
            if (jl >= ncls) continue;
            float val = (il != jl) ? acc[r][s] : finf();
            Dc[(size_t)(base + il) * MAXC + jl] = val;
            if (mirror) Dc[(size_t)(base + jl) * MAXC + il] = val;  // eps asym << tol
        }
    }
}

// ---------------- K2: per-slot top-20 + contribution -> P[slot] ----------------
// one wave per class-sorted slot; lane l holds local cols {4l..4l+3, 256+4l..}
__global__ __launch_bounds__(64) void select_kernel(const float* __restrict__ F,
                                                    const float* __restrict__ Dc,
                                                    const int* __restrict__ meta,
                                                    float* __restrict__ P,
                                                    int N, int C) {
    __shared__ int ssel[KSEL];
    const int s    = blockIdx.x;
    const int lane = threadIdx.x;

    int c = 0;
#pragma unroll
    for (int q = 1; q <= NCLS; ++q) c += (s >= meta[N + q]) ? 1 : 0;
    const int base = meta[N + c];
    const int ncls = meta[N + c + 1] - base;
    const float* drow = Dc + (size_t)s * MAXC;

    float v[8];
#pragma unroll
    for (int q = 0; q < 2; ++q) {
        float4 t = ((const float4*)drow)[q * 64 + lane];
        int col = q * 256 + 4 * lane;   // unwritten pad is 0xAA poison -> mask it
        v[q * 4 + 0] = (col + 0 < ncls) ? t.x : finf();
        v[q * 4 + 1] = (col + 1 < ncls) ? t.y : finf();
        v[q * 4 + 2] = (col + 2 < ncls) ? t.z : finf();
        v[q * 4 + 3] = (col + 3 < ncls) ? t.w : finf();
    }

    const int m = min(ncls - 1, KSEL);

    float lmin = finf();
#pragma unroll
    for (int i = 0; i < 8; ++i) lmin = fminf(lmin, v[i]);

    int mx = 0;
    for (int k = 0; k < m; ++k) {
        float w = lmin;
#pragma unroll
        for (int o = 1; o < 64; o <<= 1) w = fminf(w, __shfl_xor(w, o, 64));
        if (!(w < 1e37f)) break;        // paranoia; finite count >= m by construction
        unsigned long long mask = __ballot(lmin == w);
        int winner = (int)__builtin_ctzll(mask);
        if (lane == winner) {
            bool found = false;
            int  jl = 0;
#pragma unroll
            for (int i = 0; i < 8; ++i) {
                bool hit = !found && (v[i] == w);
                if (hit) { jl = (i >> 2) * 256 + 4 * lane + (i & 3); v[i] = finf(); found = true; }
            }
            ssel[k] = jl;
            float nm = finf();
#pragma unroll
            for (int i = 0; i < 8; ++i) nm = fminf(nm, v[i]);
            lmin = nm;
        }
        ++mx;
    }
    __syncthreads();

    float total = 0.f;
    if (mx > 0) {
        const float inv = 1.f / (float)m;     // reference divides by len(nums)=m
        const int   gi  = meta[s];
        float4 fi = ((const float4*)(F + (size_t)gi * C))[lane];
        float acc = 0.f;
        for (int k = 0; k < mx; ++k) {
            const int gj = meta[base + ssel[k]];
            float4 fj = ((const float4*)(F + (size_t)gj * C))[lane];
            float dx = fi.x - fj.x * inv;
            float dy = fi.y - fj.y * inv;
            float dz = fi.z - fj.z * inv;
            float dw = fi.w - fj.w * inv;
            acc += (dx * dx + dy * dy) + (dz * dz + dw * dw);
        }
        for (int o = 32; o > 0; o >>= 1) acc += __shfl_down(acc, o, 64);
        total = LAM_HALF * acc;
    }
    if (lane == 0) P[s] = total;
}

// ---------------- K3: out[0] = cross-entropy(mean) + sum(P) ----------------
__global__ __launch_bounds__(256) void finalize_kernel(const float* __restrict__ scores,
                                                       const int* __restrict__ target,
                                                       const float* __restrict__ P,
                                                       float* __restrict__ out,
                                                       int N, int NC) {
    int tid = threadIdx.x;
    float ce = 0.f, dg = 0.f;
    for (int r = tid; r < N; r += 256) {
        const float* sc = scores + (size_t)r * NC;
        float mx = -3.4e38f;
        for (int c = 0; c < NC; ++c) mx = fmaxf(mx, sc[c]);
        float sum = 0.f;
        for (int c = 0; c < NC; ++c) sum += __expf(sc[c] - mx);
        ce += mx + __logf(sum) - sc[target[r]];
        dg += P[r];
    }
    __shared__ float redc[4], redd[4];
    for (int o = 32; o > 0; o >>= 1) { ce += __shfl_down(ce, o, 64); dg += __shfl_down(dg, o, 64); }
    int wid = tid >> 6, lane = tid & 63;
    if (lane == 0) { redc[wid] = ce; redd[wid] = dg; }
    __syncthreads();
    if (tid == 0)
        out[0] = (redc[0] + redc[1] + redc[2] + redc[3]) / (float)N
               + (redd[0] + redd[1] + redd[2] + redd[3]);
}

extern "C" void kernel_launch(void* const* d_in, const int* in_sizes, int n_in,
                              void* d_out, int out_size, void* d_ws, size_t ws_size,
                              hipStream_t stream) {
    const float* feature = (const float*)d_in[0];
    const float* scores  = (const float*)d_in[1];
    const int*   target  = (const int*)d_in[2];
    const int N  = in_sizes[2];
    const int C  = in_sizes[0] / N;
    const int NC = in_sizes[1] / N;
    float* out = (float*)d_out;

    // ws layout: Dc (N*MAXC floats = 4 MB) | meta (N+32+528 ints) | P (N floats)
    float* Dc   = (float*)d_ws;
    int*   meta = (int*)((char*)d_ws + (size_t)N * MAXC * sizeof(float));
    float* P    = (float*)((char*)d_ws + (size_t)N * MAXC * sizeof(float) + 16384);

    setup_kernel<<<1, 256, 0, stream>>>(target, N, meta);

    // worst-case tile count: one class holding all N rows -> tri(N/64) = 528
    const int NB = N / 64;
    const int max_tiles = NB * (NB + 1) / 2;
    dist_kernel<<<max_tiles, 256, 0, stream>>>(feature, meta, Dc, N, C);

    select_kernel<<<N, 64, 0, stream>>>(feature, Dc, meta, P, N, C);

    finalize_kernel<<<1, 256, 0, stream>>>(scores, target, P, out, N, NC);
}

// Round 7
// 122.845 us; speedup vs baseline: 1.4388x; 1.0597x over previous
//
#include <hip/hip_runtime.h>
#include <math.h>

// DLP loss: ce(scores,target) + 25 * sum_i sum_{k<m_i} ||f_i - f_{nbr_k}/m_i||^2
// m_i = min(#same-label (excl self), 20), neighbors by eps-shifted L1 distance.
//
// R7 NOTE: the dominant cost is now the HARNESS's 256 MB 0xAA re-poison of d_ws
// (~40 us fillBuffer per iteration) + fixed reset/launch overhead (~90-100 us).
// Our kernels sum to ~30 us; this round halves dist's critical path by
// splitting K across two blocks per tile (two partial-D buffers, summed in
// select). Class-sorted compact layout retained from R6.
//
//  K0 setup_kernel    : 1 block. stable class-sort -> perm, cls_start, tile tab.
//  K1 dist_kernel     : 2 blocks per class-tile (K-halves), 4x4 reg blocking,
//                       b128 LDS reads, eps folded into A staging, mirror-store
//                       off-diagonal tiles. Partials -> Dc[kh] (2 x 4 MB).
//  K2 select_kernel   : 1 wave/slot, sums the two K-half partials per cell,
//                       <=20 butterfly argmin extractions, contribution -> P.
//  K3 finalize_kernel : 1 block. out[0] = cross-entropy + sum(P).

constexpr float EPS      = 1e-6f;
constexpr int   KSEL     = 20;
constexpr float LAM_HALF = 25.0f;   // 50 * 0.5
constexpr int   NCLS     = 8;

#define MAXC 512   // padded class-local row length (max class size << 512)
#define LDP  68    // LDS row stride (words): A broadcast, B 2-way (free)

__device__ __forceinline__ float finf() { return __builtin_inff(); }

// meta layout (ints), placed after Dc in ws:
//   [0, N)      perm: slot -> original row (class-grouped, index-ascending)
//   [N, N+9)    cls_start (exclusive prefix, cls_start[8] = N)
//   [N+16]      n_tiles
//   [N+32, ...) tile_tab: (class<<16)|(bi<<8)|bj, bi<=bj  (<=528 entries)

// ---------------- K0: stable class-sort + tile table ----------------
__global__ __launch_bounds__(256) void setup_kernel(const int* __restrict__ T,
                                                    int N, int* __restrict__ meta) {
    __shared__ int cnt[256 * NCLS];   // 8 KB
    __shared__ int cstart[NCLS + 1];
    const int tid = threadIdx.x;
    const int per = N / 256;          // 8 @ N=2048

    int lc[NCLS];
    int myT[16];
#pragma unroll
    for (int c = 0; c < NCLS; ++c) lc[c] = 0;
    for (int q = 0; q < per; ++q) {
        int t = T[tid * per + q];
        myT[q] = t;
        ++lc[t];
    }
#pragma unroll
    for (int c = 0; c < NCLS; ++c) cnt[tid * NCLS + c] = lc[c];
    __syncthreads();

    // per-class exclusive scan over threads (8 threads, serial over 256)
    if (tid < NCLS) {
        int off = 0;
        for (int t = 0; t < 256; ++t) {
            int v = cnt[t * NCLS + tid];
            cnt[t * NCLS + tid] = off;
            off += v;
        }
        cstart[tid] = off;            // class totals, temporarily
    }
    __syncthreads();
    if (tid == 0) {
        int tot[NCLS], acc = 0;
        for (int c = 0; c < NCLS; ++c) tot[c] = cstart[c];
        for (int c = 0; c < NCLS; ++c) { cstart[c] = acc; acc += tot[c]; }
        cstart[NCLS] = acc;           // == N
        for (int c = 0; c <= NCLS; ++c) meta[N + c] = cstart[c];
        // per-class upper-triangle 64-tile table
        int nt = 0;
        for (int c = 0; c < NCLS; ++c) {
            int nb = (tot[c] + 63) >> 6;
            for (int bi = 0; bi < nb; ++bi)
                for (int bj = bi; bj < nb; ++bj)
                    meta[N + 32 + nt++] = (c << 16) | (bi << 8) | bj;
        }
        meta[N + 16] = nt;
    }
    __syncthreads();

    // stable scatter: thread t owns contiguous rows [t*per, (t+1)*per)
    int rc[NCLS];
#pragma unroll
    for (int c = 0; c < NCLS; ++c) rc[c] = 0;
    for (int q = 0; q < per; ++q) {
        int t = myT[q];
        int pos = cstart[t] + cnt[tid * NCLS + t] + rc[t]++;
        meta[pos] = tid * per + q;
    }
}

// ---------------- K1: per-class masked pairwise eps-shifted L1 ----------------
// block = (tile, K-half). Partial over c in [kh*128, kh*128+128) -> Dc_h.
// Dc_h[slot][jl] partial; diag stored +inf in both halves (inf+inf = inf).
__global__ __launch_bounds__(256) void dist_kernel(const float* __restrict__ F,
                                                   const int* __restrict__ meta,
                                                   float* __restrict__ Dc,
                                                   int N, int C) {
    const int nt = meta[N + 16];
    const int t  = blockIdx.x >> 1;
    if (t >= nt) return;
    const int kh = blockIdx.x & 1;
    const int e    = meta[N + 32 + t];
    const int c    = e >> 16, bi = (e >> 8) & 255, bj = e & 255;
    const int base = meta[N + c];
    const int ncls = meta[N + c + 1] - base;
    const int i0 = bi * 64, j0 = bj * 64;
    const bool mirror = (bi != bj);
    float* __restrict__ Dh = Dc + (size_t)kh * N * MAXC;

    __shared__ float As[64 * LDP];
    __shared__ float Bs[64 * LDP];
    __shared__ int gi[64], gj[64];

    const int tid = threadIdx.x;
    const int tx = tid & 15, ty = tid >> 4;

    if (tid < 64)       gi[tid]      = meta[base + min(i0 + tid, ncls - 1)];
    else if (tid < 128) gj[tid - 64] = meta[base + min(j0 + (tid - 64), ncls - 1)];
    __syncthreads();

    float acc[4][4];
#pragma unroll
    for (int r = 0; r < 4; ++r)
#pragma unroll
        for (int s = 0; s < 4; ++s) acc[r][s] = 0.f;

    const int ck0 = kh * (C / 2);
    for (int ck = ck0; ck < ck0 + C / 2; ck += 64) {
#pragma unroll
        for (int it = 0; it < 4; ++it) {
            int slot = tid + it * 256;
            int row  = slot >> 4;
            int c4   = (slot & 15) << 2;
            float4 av = *(const float4*)&F[(size_t)gi[row] * C + ck + c4];
            av.x += EPS; av.y += EPS; av.z += EPS; av.w += EPS;
            *(float4*)&As[row * LDP + c4] = av;
            *(float4*)&Bs[row * LDP + c4] =
                *(const float4*)&F[(size_t)gj[row] * C + ck + c4];
        }
        __syncthreads();
#pragma unroll 4
        for (int c4 = 0; c4 < 64; c4 += 4) {
            float4 a[4], b[4];
#pragma unroll
            for (int r = 0; r < 4; ++r) a[r] = *(const float4*)&As[(ty * 4 + r) * LDP + c4];
#pragma unroll
            for (int s = 0; s < 4; ++s) b[s] = *(const float4*)&Bs[(tx + 16 * s) * LDP + c4];
#pragma unroll
            for (int r = 0; r < 4; ++r)
#pragma unroll
                for (int s = 0; s < 4; ++s) {
                    acc[r][s] += (fabsf(a[r].x - b[s].x) + fabsf(a[r].y - b[s].y))
                               + (fabsf(a[r].z - b[s].z) + fabsf(a[r].w - b[s].w));
                }
        }
        __syncthreads();
    }

#pragma unroll
    for (int r = 0; r < 4; ++r) {
        const int il = i0 + ty * 4 + r;
        if (il >= ncls) continue;
#pragma unroll
        for (int s = 0; s < 4; ++s) {
            const int jl = j0 + tx + 16 * s;
            if (jl >= ncls) continue;
            float val = (il != jl) ? acc[r][s] : finf();
            Dh[(size_t)(base + il) * MAXC + jl] = val;
            if (mirror) Dh[(size_t)(base + jl) * MAXC + il] = val;  // eps asym << tol
        }
    }
}

// ---------------- K2: per-slot top-20 + contribution -> P[slot] ----------------
// one wave per class-sorted slot; lane l holds local cols {4l..4l+3, 256+4l..}
__global__ __launch_bounds__(64) void select_kernel(const float* __restrict__ F,
                                                    const float* __restrict__ Dc,
                                                    const int* __restrict__ meta,
                                                    float* __restrict__ P,
                                                    int N, int C) {
    __shared__ int ssel[KSEL];
    const int s    = blockIdx.x;
    const int lane = threadIdx.x;

    int c = 0;
#pragma unroll
    for (int q = 1; q <= NCLS; ++q) c += (s >= meta[N + q]) ? 1 : 0;
    const int base = meta[N + c];
    const int ncls = meta[N + c + 1] - base;
    const float4* drow0 = (const float4*)(Dc + (size_t)s * MAXC);
    const float4* drow1 = (const float4*)(Dc + (size_t)(N + s) * MAXC);

    float v[8];
#pragma unroll
    for (int q = 0; q < 2; ++q) {
        float4 t0 = drow0[q * 64 + lane];
        float4 t1 = drow1[q * 64 + lane];
        int col = q * 256 + 4 * lane;   // unwritten pad is poison -> mask it
        v[q * 4 + 0] = (col + 0 < ncls) ? (t0.x + t1.x) : finf();
        v[q * 4 + 1] = (col + 1 < ncls) ? (t0.y + t1.y) : finf();
        v[q * 4 + 2] = (col + 2 < ncls) ? (t0.z + t1.z) : finf();
        v[q * 4 + 3] = (col + 3 < ncls) ? (t0.w + t1.w) : finf();
    }

    const int m = min(ncls - 1, KSEL);

    float lmin = finf();
#pragma unroll
    for (int i = 0; i < 8; ++i) lmin = fminf(lmin, v[i]);

    int mx = 0;
    for (int k = 0; k < m; ++k) {
        float w = lmin;
#pragma unroll
        for (int o = 1; o < 64; o <<= 1) w = fminf(w, __shfl_xor(w, o, 64));
        if (!(w < 1e37f)) break;        // paranoia; finite count >= m by construction
        unsigned long long mask = __ballot(lmin == w);
        int winner = (int)__builtin_ctzll(mask);
        if (lane == winner) {
            bool found = false;
            int  jl = 0;
#pragma unroll
            for (int i = 0; i < 8; ++i) {
                bool hit = !found && (v[i] == w);
                if (hit) { jl = (i >> 2) * 256 + 4 * lane + (i & 3); v[i] = finf(); found = true; }
            }
            ssel[k] = jl;
            float nm = finf();
#pragma unroll
            for (int i = 0; i < 8; ++i) nm = fminf(nm, v[i]);
            lmin = nm;
        }
        ++mx;
    }
    __syncthreads();

    float total = 0.f;
    if (mx > 0) {
        const float inv = 1.f / (float)m;     // reference divides by len(nums)=m
        const int   gi  = meta[s];
        float4 fi = ((const float4*)(F + (size_t)gi * C))[lane];
        float acc = 0.f;
        for (int k = 0; k < mx; ++k) {
            const int gj = meta[base + ssel[k]];
            float4 fj = ((const float4*)(F + (size_t)gj * C))[lane];
            float dx = fi.x - fj.x * inv;
            float dy = fi.y - fj.y * inv;
            float dz = fi.z - fj.z * inv;
            float dw = fi.w - fj.w * inv;
            acc += (dx * dx + dy * dy) + (dz * dz + dw * dw);
        }
        for (int o = 32; o > 0; o >>= 1) acc += __shfl_down(acc, o, 64);
        total = LAM_HALF * acc;
    }
    if (lane == 0) P[s] = total;
}

// ---------------- K3: out[0] = cross-entropy(mean) + sum(P) ----------------
__global__ __launch_bounds__(256) void finalize_kernel(const float* __restrict__ scores,
                                                       const int* __restrict__ target,
                                                       const float* __restrict__ P,
                                                       float* __restrict__ out,
                                                       int N, int NC) {
    int tid = threadIdx.x;
    float ce = 0.f, dg = 0.f;
    for (int r = tid; r < N; r += 256) {
        const float* sc = scores + (size_t)r * NC;
        float mx = -3.4e38f;
        for (int c = 0; c < NC; ++c) mx = fmaxf(mx, sc[c]);
        float sum = 0.f;
        for (int c = 0; c < NC; ++c) sum += __expf(sc[c] - mx);
        ce += mx + __logf(sum) - sc[target[r]];
        dg += P[r];
    }
    __shared__ float redc[4], redd[4];
    for (int o = 32; o > 0; o >>= 1) { ce += __shfl_down(ce, o, 64); dg += __shfl_down(dg, o, 64); }
    int wid = tid >> 6, lane = tid & 63;
    if (lane == 0) { redc[wid] = ce; redd[wid] = dg; }
    __syncthreads();
    if (tid == 0)
        out[0] = (redc[0] + redc[1] + redc[2] + redc[3]) / (float)N
               + (redd[0] + redd[1] + redd[2] + redd[3]);
}

extern "C" void kernel_launch(void* const* d_in, const int* in_sizes, int n_in,
                              void* d_out, int out_size, void* d_ws, size_t ws_size,
                              hipStream_t stream) {
    const float* feature = (const float*)d_in[0];
    const float* scores  = (const float*)d_in[1];
    const int*   target  = (const int*)d_in[2];
    const int N  = in_sizes[2];
    const int C  = in_sizes[0] / N;
    const int NC = in_sizes[1] / N;
    float* out = (float*)d_out;

    // ws layout: Dc (2 * N*MAXC floats = 8 MB) | meta (N+32+528 ints) | P (N floats)
    float* Dc   = (float*)d_ws;
    int*   meta = (int*)((char*)d_ws + (size_t)2 * N * MAXC * sizeof(float));
    float* P    = (float*)((char*)d_ws + (size_t)2 * N * MAXC * sizeof(float) + 16384);

    setup_kernel<<<1, 256, 0, stream>>>(target, N, meta);

    // worst-case tile count: one class holding all N rows -> tri(N/64) = 528
    const int NB = N / 64;
    const int max_tiles = NB * (NB + 1) / 2;
    dist_kernel<<<max_tiles * 2, 256, 0, stream>>>(feature, meta, Dc, N, C);

    select_kernel<<<N, 64, 0, stream>>>(feature, Dc, meta, P, N, C);

    finalize_kernel<<<1, 256, 0, stream>>>(scores, target, P, out, N, NC);
}